// Round 7
// baseline (298.814 us; speedup 1.0000x reference)
//
#include <hip/hip_runtime.h>
#include <math.h>

#define NTHREADS 256               // 4 fully-independent waves per block, no barriers
#define WPB      4                 // rows (waves) per block
#define NELEM    4096              // H*W
#define EPL      64                // keys per lane -> whole row in one wave
#define NREP     4                 // histogram replicas per wave (lane & 3)
#define RSTRIDE  260               // words per replica; %32==4 spreads replica banks
#define CBUF_OFF (NREP * RSTRIDE)  // 1040 words
#define CAP      768               // survivor cap (range compact); typical ~600
#define MAXS     (CAP / 64)        // 12 survivors per lane in registers
#define WAVE_LDS (CBUF_OFF + CAP)  // 1808 words = 7.2 KB per wave
#define LDSW     (WPB * WAVE_LDS)  // 28.9 KB/block

typedef float v4f __attribute__((ext_vector_type(4)));

// order-preserving float->uint map (ascending), branchless
__device__ __forceinline__ unsigned f2ord(float f) {
    unsigned u = __float_as_uint(f);
    return u ^ ((unsigned)((int)u >> 31) | 0x80000000u);
}
__device__ __forceinline__ float ord2f(unsigned k) {
    return __uint_as_float(k ^ (~(unsigned)((int)k >> 31) | 0x80000000u));
}

// Canonical GCN wave64 inclusive add-scan in the VALU pipe via DPP.
__device__ __forceinline__ unsigned iscan_dpp(unsigned v) {
    v += (unsigned)__builtin_amdgcn_update_dpp(0, (int)v, 0x111, 0xF, 0xF, false);
    v += (unsigned)__builtin_amdgcn_update_dpp(0, (int)v, 0x112, 0xF, 0xF, false);
    v += (unsigned)__builtin_amdgcn_update_dpp(0, (int)v, 0x114, 0xF, 0xF, false);
    v += (unsigned)__builtin_amdgcn_update_dpp(0, (int)v, 0x118, 0xF, 0xF, false);
    v += (unsigned)__builtin_amdgcn_update_dpp(0, (int)v, 0x142, 0xA, 0xF, false);
    v += (unsigned)__builtin_amdgcn_update_dpp(0, (int)v, 0x143, 0xC, 0xF, false);
    return v;
}

struct PickB { unsigned bktA, bktB, baseA; };

// Single dual-rank pick over NREP replicas of 256 bins.
// CONFLICT-FREE: b32 reads at stride-1 (bin j*64+lane), ordered prefix via
// 4 DPP scans + cross-chunk totals. Returns buckets for both ranks and the
// exclusive base (count of keys in bins < bktA) needed for local ranks.
__device__ __forceinline__ PickB pick_dual(const unsigned* hist, int lane,
                                           unsigned rA, unsigned rB) {
    unsigned s0 = 0, s1 = 0, s2 = 0, s3 = 0;
    #pragma unroll
    for (int rep = 0; rep < NREP; ++rep) {
        const unsigned* h = hist + rep * RSTRIDE;
        s0 += h[lane];
        s1 += h[64 + lane];
        s2 += h[128 + lane];
        s3 += h[192 + lane];
    }
    unsigned c0 = iscan_dpp(s0), c1 = iscan_dpp(s1);
    unsigned c2 = iscan_dpp(s2), c3 = iscan_dpp(s3);
    unsigned T0 = (unsigned)__builtin_amdgcn_readlane((int)c0, 63);
    unsigned T1 = (unsigned)__builtin_amdgcn_readlane((int)c1, 63);
    unsigned T2 = (unsigned)__builtin_amdgcn_readlane((int)c2, 63);
    unsigned e0 = c0 - s0;                 // exclusive base of bin lane
    unsigned e1 = T0 + c1 - s1;            // bin 64+lane
    unsigned e2 = T0 + T1 + c2 - s2;       // bin 128+lane
    unsigned e3 = T0 + T1 + T2 + c3 - s3;  // bin 192+lane
    unsigned ex[4]  = {e0, e1, e2, e3};
    unsigned cnt[4] = {s0, s1, s2, s3};
    unsigned resA = 0, resB = 0;
    bool fA = false, fB = false;
    #pragma unroll
    for (int j = 0; j < 4; ++j) {
        unsigned bin = (unsigned)(j * 64 + lane);
        if (rA >= ex[j] && rA < ex[j] + cnt[j]) { resA = (bin << 13) | ex[j]; fA = true; }
        if (rB >= ex[j] && rB < ex[j] + cnt[j]) { resB = (bin << 13) | ex[j]; fB = true; }
    }
    unsigned long long mA = __ballot(fA);
    unsigned long long mB = __ballot(fB);
    unsigned a = (unsigned)__builtin_amdgcn_readlane((int)resA, (int)(__ffsll((long long)mA) - 1));
    unsigned b = (unsigned)__builtin_amdgcn_readlane((int)resB, (int)(__ffsll((long long)mB) - 1));
    PickB r;
    r.bktA = a >> 13; r.baseA = a & 0x1FFFu; r.bktB = b >> 13;
    return r;
}

__global__ void __launch_bounds__(NTHREADS, 4)
xsrelu_kernel(const float* __restrict__ x, const float* __restrict__ plogit,
              float* __restrict__ out, int C, int nrows) {
    __shared__ __align__(16) unsigned lds[LDSW];   // wave-private, no barriers

    const int tid  = threadIdx.x;
    const int wid  = tid >> 6;
    const int lane = tid & 63;
    const int row  = blockIdx.x * WPB + wid;
    if (row >= nrows) return;                      // wave-uniform

    unsigned* wbase = lds + wid * WAVE_LDS;
    unsigned* cbuf  = wbase + CBUF_OFF;

    // ---- Load row once (coalesced float4); keys in registers.
    const float4* xr = (const float4*)(x + (size_t)row * NELEM);
    unsigned k[EPL];
    #pragma unroll
    for (int j = 0; j < EPL / 4; ++j) {
        float4 v = xr[j * 64 + lane];
        k[4 * j + 0] = f2ord(v.x);
        k[4 * j + 1] = f2ord(v.y);
        k[4 * j + 2] = f2ord(v.z);
        k[4 * j + 3] = f2ord(v.w);
    }

    // Row-uniform scalars.
    float p0 = 1.0f / (1.0f + expf(-plogit[0]));
    float pc = 1.0f / (1.0f + expf(-plogit[row % C]));
    unsigned kLow  = (unsigned)min(max((int)((float)NELEM * (p0 - 0.02f)), 0), NELEM - 1);
    unsigned kHigh = (unsigned)min(max((int)((float)NELEM * (p0 + 0.02f)), 0), NELEM - 1);

    // ---- ONE histogram pass (bits 31..24). Zero via stride-1 b32 (conflict-free).
    #pragma unroll
    for (int r = 0; r < NREP; ++r) {
        unsigned* h = wbase + r * RSTRIDE;
        h[lane] = 0u; h[64 + lane] = 0u; h[128 + lane] = 0u; h[192 + lane] = 0u;
    }
    unsigned* my = wbase + (lane & (NREP - 1)) * RSTRIDE;
    #pragma unroll
    for (int j = 0; j < EPL; ++j)
        atomicAdd(&my[k[j] >> 24], 1u);

    // Same-wave DS program order: atomics complete before pick reads — no barrier.
    PickB p = pick_dual(wbase, lane, kLow, kHigh);
    unsigned bktA = p.bktA, bktB = p.bktB, baseA = p.baseA;
    unsigned span = bktB - bktA;                   // bktA <= bktB always

    // ---- Range-compact keys with top byte in [bktA, bktB] (handles A!=B natively).
    unsigned mlo = 0u, mhi = 0u, mycnt = 0u;
    #pragma unroll
    for (int j = 0; j < EPL; ++j) {
        bool m = ((k[j] >> 24) - bktA) <= span;    // unsigned wrap rejects < bktA
        mycnt += m ? 1u : 0u;
        if (j < 32) mlo |= m ? (1u << j) : 0u;
        else        mhi |= m ? (1u << (j - 32)) : 0u;
    }
    unsigned inc  = iscan_dpp(mycnt);
    unsigned scnt = (unsigned)__builtin_amdgcn_readlane((int)inc, 63);

    unsigned keyA, keyB;
    if (scnt <= CAP) {                             // wave-uniform branch
        unsigned wpos = inc - mycnt;               // exclusive base for this lane
        #pragma unroll
        for (int j = 0; j < EPL; ++j) {
            bool m = (j < 32) ? ((mlo >> j) & 1u) : ((mhi >> (j - 32)) & 1u);
            if (m) { cbuf[wpos] = k[j]; ++wpos; }
        }
        // Readback lane-major (stride-1, conflict-free); pad sorts above all.
        unsigned S[MAXS];
        #pragma unroll
        for (int j = 0; j < MAXS; ++j) {
            unsigned idx = (unsigned)(j * 64 + lane);
            unsigned w = cbuf[idx];
            S[j] = (idx < scnt) ? w : 0xFFFFFFFFu;
        }
        // ---- 24-bit dual bit-descend, ballot+popcount (VALU+SALU, zero LDS).
        unsigned pA = bktA << 24, pB = bktB << 24;
        unsigned lrA = kLow - baseA, lrB = kHigh - baseA;   // ranks rel. to range start
        #pragma unroll 1
        for (int b = 23; b >= 0; --b) {
            unsigned cA = pA | (1u << b), cB = pB | (1u << b);
            unsigned nA = 0, nB = 0;
            #pragma unroll
            for (int j = 0; j < MAXS; ++j) {
                nA += (unsigned)__popcll(__ballot(S[j] < cA));
                nB += (unsigned)__popcll(__ballot(S[j] < cB));
            }
            if (nA <= lrA) pA = cA;                // wave-uniform (ballot counts)
            if (nB <= lrB) pB = cB;
        }
        keyA = pA; keyB = pB;
    } else {
        // Degenerate rows (>CAP in range): descend over ALL register keys with
        // GLOBAL ranks. count(k < bkt<<24) = base <= rank holds by pick.
        unsigned pA = bktA << 24, pB = bktB << 24;
        #pragma unroll 1
        for (int b = 23; b >= 0; --b) {
            unsigned cA = pA | (1u << b), cB = pB | (1u << b);
            unsigned nA = 0, nB = 0;
            #pragma unroll
            for (int j = 0; j < EPL; ++j) {
                nA += (unsigned)__popcll(__ballot(k[j] < cA));
                nB += (unsigned)__popcll(__ballot(k[j] < cB));
            }
            if (nA <= kLow)  pA = cA;
            if (nB <= kHigh) pB = cB;
        }
        keyA = pA; keyB = pB;
    }

    float xlow  = ord2f(keyA);
    float xhigh = ord2f(keyB);
    float thr = xlow + (xhigh - xlow) * pc;

    // ---- Epilogue: relu(x - thr) from register keys; nontemporal stream out.
    v4f* outr = (v4f*)(out + (size_t)row * NELEM);
    #pragma unroll
    for (int j = 0; j < EPL / 4; ++j) {
        v4f o;
        o.x = fmaxf(ord2f(k[4 * j + 0]) - thr, 0.0f);
        o.y = fmaxf(ord2f(k[4 * j + 1]) - thr, 0.0f);
        o.z = fmaxf(ord2f(k[4 * j + 2]) - thr, 0.0f);
        o.w = fmaxf(ord2f(k[4 * j + 3]) - thr, 0.0f);
        __builtin_nontemporal_store(o, outr + j * 64 + lane);
    }
}

extern "C" void kernel_launch(void* const* d_in, const int* in_sizes, int n_in,
                              void* d_out, int out_size, void* d_ws, size_t ws_size,
                              hipStream_t stream) {
    const float* x      = (const float*)d_in[0];
    const float* plogit = (const float*)d_in[1];
    float* out          = (float*)d_out;
    int C    = in_sizes[1];              // 256
    int rows = in_sizes[0] / NELEM;      // 8192
    int grid = (rows + WPB - 1) / WPB;   // 2048 blocks
    xsrelu_kernel<<<grid, NTHREADS, 0, stream>>>(x, plogit, out, C, rows);
}

// Round 9
// 282.558 us; speedup vs baseline: 1.0575x; 1.0575x over previous
//
#include <hip/hip_runtime.h>
#include <math.h>

#define NTHREADS 256               // 4 waves cooperate on one row at a time
#define ROWS_PB  8                 // rows per block, software-pipelined via DMA
#define NELEM    4096              // H*W
#define QUART    1024              // floats per wave quarter
#define KPL      16                // keys per lane (quarter / 64)
#define NREP     4                 // one histogram replica per wave
#define HSTRIDE  260               // words; %32==4 spreads replica base banks
#define HISTW    (NREP * HSTRIDE)  // 1040 words
// LDS: 2*16KB row buffers + 4.2KB hist = 36928 B -> 4 blocks/CU

// Wave drains its OWN LDS ops, then block barrier (builtin: visible to the
// compiler's convergence analysis). NEVER drains vmcnt — DMA stays in flight.
__device__ __forceinline__ void syncw() {
    asm volatile("s_waitcnt lgkmcnt(0)" ::: "memory");
    __builtin_amdgcn_s_barrier();
}
__device__ __forceinline__ void wait_vm(int n) {
    switch (n) {                   // immediate must be literal in the asm string
        case 0:  asm volatile("s_waitcnt vmcnt(0)"  ::: "memory"); break;
        case 4:  asm volatile("s_waitcnt vmcnt(4)"  ::: "memory"); break;
        case 16: asm volatile("s_waitcnt vmcnt(16)" ::: "memory"); break;
        default: asm volatile("s_waitcnt vmcnt(20)" ::: "memory"); break;
    }
    __builtin_amdgcn_sched_barrier(0);   // rule-#18 insurance: nothing hoists past
}

// order-preserving float->uint map (ascending), branchless
__device__ __forceinline__ unsigned f2ord(float f) {
    unsigned u = __float_as_uint(f);
    return u ^ ((unsigned)((int)u >> 31) | 0x80000000u);
}
__device__ __forceinline__ float ord2f(unsigned k) {
    return __uint_as_float(k ^ (~(unsigned)((int)k >> 31) | 0x80000000u));
}

// Canonical GCN wave64 inclusive add-scan in the VALU pipe via DPP.
__device__ __forceinline__ unsigned iscan_dpp(unsigned v) {
    v += (unsigned)__builtin_amdgcn_update_dpp(0, (int)v, 0x111, 0xF, 0xF, false);
    v += (unsigned)__builtin_amdgcn_update_dpp(0, (int)v, 0x112, 0xF, 0xF, false);
    v += (unsigned)__builtin_amdgcn_update_dpp(0, (int)v, 0x114, 0xF, 0xF, false);
    v += (unsigned)__builtin_amdgcn_update_dpp(0, (int)v, 0x118, 0xF, 0xF, false);
    v += (unsigned)__builtin_amdgcn_update_dpp(0, (int)v, 0x142, 0xA, 0xF, false);
    v += (unsigned)__builtin_amdgcn_update_dpp(0, (int)v, 0x143, 0xC, 0xF, false);
    return v;
}

struct PickR { unsigned binA, baseA, binB, baseB; };

// Dual-rank pick over NREP replicas of 256 bins. CONFLICT-FREE stride-1 b32
// reads (R7-proven). Returns bin and exclusive base for BOTH ranks. All waves
// run this redundantly on shared hist -> identical wave-uniform results.
__device__ __forceinline__ PickR pick_dual(const unsigned* h, int lane,
                                           unsigned rA, unsigned rB) {
    unsigned s0 = 0, s1 = 0, s2 = 0, s3 = 0;
    #pragma unroll
    for (int rep = 0; rep < NREP; ++rep) {
        const unsigned* r = h + rep * HSTRIDE;
        s0 += r[lane]; s1 += r[64 + lane]; s2 += r[128 + lane]; s3 += r[192 + lane];
    }
    unsigned c0 = iscan_dpp(s0), c1 = iscan_dpp(s1);
    unsigned c2 = iscan_dpp(s2), c3 = iscan_dpp(s3);
    unsigned T0 = (unsigned)__builtin_amdgcn_readlane((int)c0, 63);
    unsigned T1 = (unsigned)__builtin_amdgcn_readlane((int)c1, 63);
    unsigned T2 = (unsigned)__builtin_amdgcn_readlane((int)c2, 63);
    unsigned ex[4] = {c0 - s0, T0 + c1 - s1, T0 + T1 + c2 - s2, T0 + T1 + T2 + c3 - s3};
    unsigned cn[4] = {s0, s1, s2, s3};
    unsigned resA = 0, resB = 0;
    bool fA = false, fB = false;
    #pragma unroll
    for (int j = 0; j < 4; ++j) {
        unsigned bin = (unsigned)(j * 64 + lane);
        if (rA >= ex[j] && rA < ex[j] + cn[j]) { resA = (bin << 13) | ex[j]; fA = true; }
        if (rB >= ex[j] && rB < ex[j] + cn[j]) { resB = (bin << 13) | ex[j]; fB = true; }
    }
    unsigned long long mA = __ballot(fA);
    unsigned long long mB = __ballot(fB);
    unsigned a = (unsigned)__builtin_amdgcn_readlane((int)resA, (int)(__ffsll((long long)mA) - 1));
    unsigned b = (unsigned)__builtin_amdgcn_readlane((int)resB, (int)(__ffsll((long long)mB) - 1));
    PickR r;
    r.binA = a >> 13; r.baseA = a & 0x1FFFu;
    r.binB = b >> 13; r.baseB = b & 0x1FFFu;
    return r;
}

// Async DMA of one wave quarter (4KB) into LDS: 4 x global_load_lds width=16.
// LDS dest is WAVE-UNIFORM base (HW adds lane*16); global src is per-lane.
__device__ __forceinline__ void dma4(const float* g, float* l, int lane) {
    #pragma unroll
    for (int i = 0; i < 4; ++i) {
        __builtin_amdgcn_global_load_lds(
            (const __attribute__((address_space(1))) void*)(g + i * 256 + lane * 4),
            (__attribute__((address_space(3))) void*)(l + i * 256),
            16, 0, 0);
    }
}

__global__ void __launch_bounds__(NTHREADS, 4)
xsrelu_kernel(const float* __restrict__ x, const float* __restrict__ plogit,
              float* __restrict__ out, int C, int nrows) {
    __shared__ __align__(16) float    buf[2][NELEM];   // double-buffered row
    __shared__ __align__(16) unsigned hist[HISTW];

    const int tid  = threadIdx.x;
    const int wid  = tid >> 6;
    const int lane = tid & 63;
    const int row0 = blockIdx.x * ROWS_PB;
    if (row0 >= nrows) return;                          // block-uniform
    const int rp = min(ROWS_PB, nrows - row0);

    // Row-set-uniform scalars.
    float p0 = 1.0f / (1.0f + expf(-plogit[0]));
    unsigned kLow  = (unsigned)min(max((int)((float)NELEM * (p0 - 0.02f)), 0), NELEM - 1);
    unsigned kHigh = (unsigned)min(max((int)((float)NELEM * (p0 + 0.02f)), 0), NELEM - 1);

    unsigned* rep = hist + wid * HSTRIDE;               // wave-private replica

    // Prologue: start row 0 DMA.
    dma4(x + (size_t)row0 * NELEM + wid * QUART, buf[0] + wid * QUART, lane);

    #pragma unroll 1
    for (int n = 0; n < rp; ++n) {
        // 1. Issue next row's DMA immediately (flies under this row's selection).
        if (n + 1 < rp)
            dma4(x + (size_t)(row0 + n + 1) * NELEM + wid * QUART,
                 buf[(n + 1) & 1] + wid * QUART, lane);

        // 2. Counted vmcnt wait: row n's 4 loads retired; newer loads (4) and
        //    older stores (16) may REMAIN in flight (in-flight order is
        //    [row-n loads][pc load][stores n-1][row-n+1 loads], so retiring
        //    down to 20 always covers row n's loads).
        if (n == 0)            wait_vm(rp > 1 ? 4 : 0);
        else if (n + 1 < rp)   wait_vm(20);
        else                   wait_vm(16);

        // 3. Keys: stride-1 conflict-free reads of OWN quarter (own DMA data).
        const float* bc = buf[n & 1] + wid * QUART;
        unsigned k[KPL];
        #pragma unroll
        for (int j = 0; j < KPL; ++j)
            k[j] = f2ord(bc[j * 64 + lane]);

        // 4. Pass 1 (bits 31..24): wave-private zero -> atomics (program order).
        rep[lane] = 0u; rep[64 + lane] = 0u; rep[128 + lane] = 0u; rep[192 + lane] = 0u;
        #pragma unroll
        for (int j = 0; j < KPL; ++j)
            atomicAdd(&rep[k[j] >> 24], 1u);
        syncw();
        PickR p = pick_dual(hist, lane, kLow, kHigh);
        syncw();                                         // picks read before re-zero
        unsigned prefA = p.binA << 24, lrA = kLow  - p.baseA;
        unsigned prefB = p.binB << 24, lrB = kHigh - p.baseB;
        int divshift = (p.binA != p.binB) ? 24 : -1;
        unsigned maskA = 0xFF000000u;

        // Passes 2..4 for A (B rides along until divergence).
        #pragma unroll 1
        for (int shift = 16; shift >= 0; shift -= 8) {
            rep[lane] = 0u; rep[64 + lane] = 0u; rep[128 + lane] = 0u; rep[192 + lane] = 0u;
            #pragma unroll
            for (int j = 0; j < KPL; ++j)
                if ((k[j] & maskA) == prefA)
                    atomicAdd(&rep[(k[j] >> shift) & 0xFFu], 1u);
            syncw();
            if (divshift < 0) {
                PickR q = pick_dual(hist, lane, lrA, lrB);
                syncw();
                prefA |= q.binA << shift; lrA -= q.baseA;
                prefB |= q.binB << shift; lrB -= q.baseB;
                if (q.binA != q.binB) divshift = shift;
            } else {
                PickR q = pick_dual(hist, lane, lrA, lrA);
                syncw();
                prefA |= q.binA << shift; lrA -= q.baseA;
            }
            maskA |= 0xFFu << shift;
        }

        // Rare (bucket-split) B continuation: remaining digits below divergence.
        if (divshift > 0) {                              // block-uniform branch
            unsigned maskB = 0xFFFFFFFFu << divshift;
            #pragma unroll 1
            for (int shift = divshift - 8; shift >= 0; shift -= 8) {
                rep[lane] = 0u; rep[64 + lane] = 0u; rep[128 + lane] = 0u; rep[192 + lane] = 0u;
                #pragma unroll
                for (int j = 0; j < KPL; ++j)
                    if ((k[j] & maskB) == prefB)
                        atomicAdd(&rep[(k[j] >> shift) & 0xFFu], 1u);
                syncw();
                PickR q = pick_dual(hist, lane, lrB, lrB);
                syncw();
                prefB |= q.binA << shift; lrB -= q.baseA;
                maskB |= 0xFFu << shift;
            }
        }

        // 5. Epilogue: relu from register keys; fire-and-forget streaming stores.
        int row = row0 + n;
        float pc = 1.0f / (1.0f + expf(-plogit[row % C]));
        float xlow = ord2f(prefA), xhigh = ord2f(prefB);
        float thr = xlow + (xhigh - xlow) * pc;
        float* orow = out + (size_t)row * NELEM + wid * QUART;
        #pragma unroll
        for (int j = 0; j < KPL; ++j)
            __builtin_nontemporal_store(fmaxf(ord2f(k[j]) - thr, 0.0f),
                                        &orow[j * 64 + lane]);
    }
}

extern "C" void kernel_launch(void* const* d_in, const int* in_sizes, int n_in,
                              void* d_out, int out_size, void* d_ws, size_t ws_size,
                              hipStream_t stream) {
    const float* x      = (const float*)d_in[0];
    const float* plogit = (const float*)d_in[1];
    float* out          = (float*)d_out;
    int C    = in_sizes[1];                        // 256
    int rows = in_sizes[0] / NELEM;                // 8192
    int grid = (rows + ROWS_PB - 1) / ROWS_PB;     // 1024 blocks, 4/CU resident
    xsrelu_kernel<<<grid, NTHREADS, 0, stream>>>(x, plogit, out, C, rows);
}